// Round 10
// baseline (425.099 us; speedup 1.0000x reference)
//
#include <hip/hip_runtime.h>

// LSTM autoencoder: 4 layers 64->64, B=512, T=256 — fused, single barrier/tick.
//
// 256 blocks x 512 threads (1 block/CU). Block = 2 batch elements x 4 layers.
// Wave w = (layer L = w>>1, unit-half mh = w&1) owns all 4 gates of units
// [mh*32, mh*32+32) via gate-split M-tiles (g=0..3, j=0..1).
// Per tick tau (layer L at t = tau-L):
//   1. read h (and v = h_{L-1} | x) fragments from LDS parity (tau+1)&1
//   2. 32 MFMA (16x16x32 f16), bias pre-folded into C-init (Cb)
//   3. gates to per-wave LDS as FOUR b32 PLANES, word = g*64 + u'*2 + el:
//      write banks q*8+r*2+n (8 distinct, conflict-free), straight from C
//      registers (no float4 assembly); reads are exact 2-way (free).
//      Same-wave ds ordering via lgkmcnt — NO barrier.
//   4. epilogue 1 unit/lane (10 trans over 64 lanes), h -> Hb parity buffer,
//      L3 stores out coalesced; ONE __syncthreads() per tick.
// L0's x prefetched one tick ahead into statically-named f32 regs.

typedef _Float16 f16x8 __attribute__((ext_vector_type(8)));
typedef float    f32x4 __attribute__((ext_vector_type(4)));

#define TSEQ 256

__device__ __forceinline__ float fast_rcp(float x) { return __builtin_amdgcn_rcpf(x); }
__device__ __forceinline__ float sigm(float x) { return fast_rcp(1.0f + __expf(-x)); }
__device__ __forceinline__ float tanh_fast(float x) {
    return 2.0f * fast_rcp(1.0f + __expf(-2.0f * x)) - 1.0f;
}
__device__ __forceinline__ f16x8 cvt8(float4 a, float4 b) {
    f16x8 f;
    f[0] = (_Float16)a.x; f[1] = (_Float16)a.y; f[2] = (_Float16)a.z; f[3] = (_Float16)a.w;
    f[4] = (_Float16)b.x; f[5] = (_Float16)b.y; f[6] = (_Float16)b.z; f[7] = (_Float16)b.w;
    return f;
}

__global__ __launch_bounds__(512, 2)
void lstm_fused6(const float* __restrict__ x,     // [512, 256, 64]
                 float* __restrict__ out,         // [512, 256, 64]
                 const float* __restrict__ Wih0, const float* __restrict__ Whh0,
                 const float* __restrict__ bi0,  const float* __restrict__ bh0,
                 const float* __restrict__ Wih1, const float* __restrict__ Whh1,
                 const float* __restrict__ bi1,  const float* __restrict__ bh1,
                 const float* __restrict__ Wih2, const float* __restrict__ Whh2,
                 const float* __restrict__ bi2,  const float* __restrict__ bh2,
                 const float* __restrict__ Wih3, const float* __restrict__ Whh3,
                 const float* __restrict__ bi3,  const float* __restrict__ bh3)
{
    __shared__ float    Gp[8 * 256];         // 8 KB: [wave][gate g][u'*2 + el]
    __shared__ _Float16 Hb[2][4][2][64];     // 2 KB: parity, layer, el, unit

    const int tid  = threadIdx.x;
    const int wave = tid >> 6;
    const int lane = tid & 63;
    const int L    = wave >> 1;     // layer 0..3
    const int mh   = wave & 1;      // unit-half: units [mh*32, mh*32+32)
    const int q    = lane >> 4;     // quad
    const int n    = lane & 15;     // MFMA col; valid batch cols are n<2
    const int b0   = blockIdx.x * 2;

    const float* Wih = (L == 0) ? Wih0 : (L == 1) ? Wih1 : (L == 2) ? Wih2 : Wih3;
    const float* Whh = (L == 0) ? Whh0 : (L == 1) ? Whh1 : (L == 2) ? Whh2 : Whh3;
    const float* bi  = (L == 0) ? bi0  : (L == 1) ? bi1  : (L == 2) ? bi2  : bi3;
    const float* bh  = (L == 0) ? bh0  : (L == 1) ? bh1  : (L == 2) ? bh2  : bh3;

    // ---- persistent A-fragments: tile (g,j) = rows g*64+mh*32+j*16+[0,16) ----
    // A layout: A[m=lane&15][k=q*8+kk]; bias folded into C-init Cb[g][j].
    f16x8 Aih[4][2][2], Ahh[4][2][2];
    f32x4 Cb[4][2];
#pragma unroll
    for (int g = 0; g < 4; ++g) {
#pragma unroll
        for (int j = 0; j < 2; ++j) {
            const int row = g * 64 + mh * 32 + j * 16 + n;
#pragma unroll
            for (int c = 0; c < 2; ++c) {
                const float* pi = Wih + row * 64 + c * 32 + q * 8;
                const float* ph = Whh + row * 64 + c * 32 + q * 8;
                f16x8 fi, fh;
#pragma unroll
                for (int k = 0; k < 8; ++k) { fi[k] = (_Float16)pi[k]; fh[k] = (_Float16)ph[k]; }
                Aih[g][j][c] = fi;
                Ahh[g][j][c] = fh;
            }
            f32x4 cb;
#pragma unroll
            for (int r = 0; r < 4; ++r) {
                const int br = g * 64 + mh * 32 + j * 16 + q * 4 + r;
                cb[r] = bi[br] + bh[br];
            }
            Cb[g][j] = cb;
        }
    }

    // ---- epilogue identity: lane owns (el = lane>>5, unit = mh*32+(lane&31)) ----
    const int el   = lane >> 5;
    const int unit = mh * 32 + (lane & 31);
    const int gidx = wave * 256 + ((lane & 31) << 1) + el;   // plane-0 read word
    const int wbase = wave * 256 + ((q * 4) << 1) + n;       // write word base
    float cst = 0.0f;
    float* outp = out + ((size_t)(b0 + el) * TSEQ) * 64 + unit;   // L==3 only

    // ---- zero h state (both parities): 2048 B = 512 ints ----
    ((int*)Hb)[tid] = 0;

    // ---- L0 x prefetch: raw f32 one tick ahead (lanes n<2 only) ----
    const float* xbase = x + ((size_t)(b0 + (n & 1)) * TSEQ) * 64 + q * 8;
    float4 R0, R1, R2, R3;
    R0 = R1 = R2 = R3 = make_float4(0.f, 0.f, 0.f, 0.f);
    if (L == 0 && n < 2) {
        R0 = *(const float4*)(xbase);      R1 = *(const float4*)(xbase + 4);
        R2 = *(const float4*)(xbase + 32); R3 = *(const float4*)(xbase + 36);
    }

    __syncthreads();

    for (int tau = 0; tau < TSEQ + 3; ++tau) {
        const int  t   = tau - L;
        const bool act = (unsigned)t < TSEQ;   // wave-uniform
        const int  pr  = (tau + 1) & 1;
        const int  pw  = tau & 1;

        if (act) {
            // ---- input fragments ----
            f16x8 vf0, vf1;
            if (L == 0) {
                vf0 = cvt8(R0, R1);            // x(t)
                vf1 = cvt8(R2, R3);
                if (t + 1 < TSEQ && n < 2) {   // prefetch x(t+1)
                    const float* p = xbase + (t + 1) * 64;
                    R0 = *(const float4*)(p);      R1 = *(const float4*)(p + 4);
                    R2 = *(const float4*)(p + 32); R3 = *(const float4*)(p + 36);
                }
            } else {
                const _Float16* vp = &Hb[pr][L - 1][n & 1][0];
                vf0 = *(const f16x8*)(vp + q * 8);
                vf1 = *(const f16x8*)(vp + 32 + q * 8);
            }
            const _Float16* hp = &Hb[pr][L][n & 1][0];
            f16x8 hf0 = *(const f16x8*)(hp + q * 8);
            f16x8 hf1 = *(const f16x8*)(hp + 32 + q * 8);

            // ---- 32 MFMA; gate-plane b32 writes issue per finished tile ----
#pragma unroll
            for (int j = 0; j < 2; ++j) {
#pragma unroll
                for (int g = 0; g < 4; ++g) {
                    f32x4 c = Cb[g][j];
                    c = __builtin_amdgcn_mfma_f32_16x16x32_f16(Ahh[g][j][0], hf0, c, 0, 0, 0);
                    c = __builtin_amdgcn_mfma_f32_16x16x32_f16(Ahh[g][j][1], hf1, c, 0, 0, 0);
                    c = __builtin_amdgcn_mfma_f32_16x16x32_f16(Aih[g][j][0], vf0, c, 0, 0, 0);
                    c = __builtin_amdgcn_mfma_f32_16x16x32_f16(Aih[g][j][1], vf1, c, 0, 0, 0);
                    if (n < 2) {
                        // word = wave*256 + g*64 + (j*16+q*4+r)*2 + n
                        // banks q*8+r*2+n: 8 distinct -> conflict-free
#pragma unroll
                        for (int r = 0; r < 4; ++r)
                            Gp[wbase + g * 64 + (j * 16 + r) * 2] = c[r];
                    }
                }
            }

            // ---- same-wave redistribute: 1 (unit,el) per lane (2-way = free) ----
            float pi = Gp[gidx];
            float pf = Gp[gidx + 64];
            float pg = Gp[gidx + 128];
            float po = Gp[gidx + 192];

            float gi = sigm(pi);
            float gf = sigm(pf);
            float gg = tanh_fast(pg);
            float go = sigm(po);
            cst = gf * cst + gi * gg;
            float h = go * tanh_fast(cst);

            if (L == 3) outp[t * 64] = h;
            Hb[pw][L][el][unit] = (_Float16)h;
        }
        __syncthreads();
    }
}

extern "C" void kernel_launch(void* const* d_in, const int* in_sizes, int n_in,
                              void* d_out, int out_size, void* d_ws, size_t ws_size,
                              hipStream_t stream) {
    const float* x = (const float*)d_in[0];
    float* out = (float*)d_out;

    lstm_fused6<<<256, 512, 0, stream>>>(
        x, out,
        (const float*)d_in[1],  (const float*)d_in[2],
        (const float*)d_in[3],  (const float*)d_in[4],
        (const float*)d_in[5],  (const float*)d_in[6],
        (const float*)d_in[7],  (const float*)d_in[8],
        (const float*)d_in[9],  (const float*)d_in[10],
        (const float*)d_in[11], (const float*)d_in[12],
        (const float*)d_in[13], (const float*)d_in[14],
        (const float*)d_in[15], (const float*)d_in[16]);
}